// Round 20
// baseline (102.175 us; speedup 1.0000x reference)
//
#include <hip/hip_runtime.h>

#define NN   16000
#define NE   64000
#define DIN  256
#define HD   64
#define DOUT 256
#define DE   128
#define KHD  32
#define DCAP 32
#define BN_EPS 1e-5f
#define LNS 264
#define EIS 136
#define HS  36
#define UTS 72

typedef __attribute__((ext_vector_type(8))) short bf16x8;
typedef __attribute__((ext_vector_type(4))) float f32x4;

__device__ __forceinline__ unsigned short f2bf(float f) {
    unsigned int u = __float_as_uint(f);
    u += 0x7fff + ((u >> 16) & 1);
    return (unsigned short)(u >> 16);
}
__device__ __forceinline__ float bf2f(unsigned short s) {
    return __uint_as_float(((unsigned int)s) << 16);
}

// ---------------- kernel PW: pack only w1b/kw1b (needed by k_mh) -------------------------
__global__ __launch_bounds__(256) void k_prepw(
    const float* __restrict__ w1, const float* __restrict__ kw1,
    unsigned short* __restrict__ w1b, unsigned short* __restrict__ kw1b)
{
    int idx = blockIdx.x * 256 + threadIdx.x;
    if (idx < 16384) { int j = idx >> 8, k = idx & 255; w1b[idx] = f2bf(w1[(size_t)k * 64 + j]); return; }
    idx -= 16384;
    if (idx < 4096) { int h = idx >> 7, k = idx & 127; kw1b[idx] = f2bf(kw1[(size_t)k * 32 + h]); }
}

// ---------------- kernel MH: msgn | hidden | pack + zero cnt & cnt2 ----------------------
__global__ __launch_bounds__(256) void k_mh(
    const float* __restrict__ x, const unsigned short* __restrict__ w1b,
    const float* __restrict__ b1,
    const float* __restrict__ g_in, const float* __restrict__ be_in,
    const float* __restrict__ m_in, const float* __restrict__ v_in,
    const float* __restrict__ g_m, const float* __restrict__ be_m,
    const float* __restrict__ m_m, const float* __restrict__ v_m,
    unsigned short* __restrict__ msgn_b,
    const float* __restrict__ ei, const unsigned short* __restrict__ kw1b,
    const float* __restrict__ kb1, unsigned short* __restrict__ hid_b,
    const float* __restrict__ kw2, const float* __restrict__ kb2,
    const float* __restrict__ w2,
    unsigned short* __restrict__ Wb2, unsigned short* __restrict__ W0b,
    unsigned short* __restrict__ w2b, int* __restrict__ cnt, int* __restrict__ cnt2)
{
    __shared__ __align__(16) unsigned char smem[36608];
    const int t = threadIdx.x;
    const int w = t >> 6, le = t & 15, g = (t >> 4) & 3;
    const f32x4 zz = {0.f, 0.f, 0.f, 0.f};

    if (blockIdx.x < NN / 64) {
        // ---------------- msgn branch ----------------
        unsigned short* lnb = (unsigned short*)smem;
        float* sc_in = (float*)(smem + 33792);
        float* sh_in = (float*)(smem + 34816);
        float* sc_m  = (float*)(smem + 35840);
        float* shm2  = (float*)(smem + 36096);
        const int n0 = blockIdx.x * 64;
        {
            float s = g_in[t] * rsqrtf(v_in[t] + BN_EPS);
            sc_in[t] = s; sh_in[t] = be_in[t] - m_in[t] * s;
            if (t < HD) {
                float s2 = g_m[t] * rsqrtf(v_m[t] + BN_EPS);
                sc_m[t] = s2; shm2[t] = b1[t] * s2 + (be_m[t] - m_m[t] * s2);
            }
        }
        __syncthreads();
        for (int i = t; i < 64 * 64; i += 256) {
            int row = i >> 6, c4 = (i & 63) * 4;
            float4 xx = *(const float4*)(x + (size_t)(n0 + row) * DIN + c4);
            float4 sc = *(const float4*)(sc_in + c4);
            float4 sh = *(const float4*)(sh_in + c4);
            ushort4 o;
            o.x = f2bf(fmaxf(fmaf(xx.x, sc.x, sh.x), 0.f));
            o.y = f2bf(fmaxf(fmaf(xx.y, sc.y, sh.y), 0.f));
            o.z = f2bf(fmaxf(fmaf(xx.z, sc.z, sh.z), 0.f));
            o.w = f2bf(fmaxf(fmaf(xx.w, sc.w, sh.w), 0.f));
            *(ushort4*)(lnb + row * LNS + c4) = o;
        }
        __syncthreads();
        f32x4 acc[4] = {zz, zz, zz, zz};
#pragma unroll
        for (int ks = 0; ks < 8; ++ks) {
            bf16x8 b = *(const bf16x8*)(lnb + (w * 16 + le) * LNS + ks * 32 + g * 8);
#pragma unroll
            for (int jt = 0; jt < 4; ++jt) {
                bf16x8 a = *(const bf16x8*)(w1b + (jt * 16 + le) * 256 + ks * 32 + g * 8);
                acc[jt] = __builtin_amdgcn_mfma_f32_16x16x32_bf16(a, b, acc[jt], 0, 0, 0);
            }
        }
        const int n = n0 + w * 16 + le;
#pragma unroll
        for (int jt = 0; jt < 4; ++jt) {
            int j = jt * 16 + g * 4;
            float4 sc = *(const float4*)(sc_m + j);
            float4 sh = *(const float4*)(shm2 + j);
            ushort4 o;
            o.x = f2bf(fmaxf(fmaf(acc[jt][0], sc.x, sh.x), 0.f));
            o.y = f2bf(fmaxf(fmaf(acc[jt][1], sc.y, sh.y), 0.f));
            o.z = f2bf(fmaxf(fmaf(acc[jt][2], sc.z, sh.z), 0.f));
            o.w = f2bf(fmaxf(fmaf(acc[jt][3], sc.w, sh.w), 0.f));
            *(ushort4*)(msgn_b + (size_t)n * HD + j) = o;
        }
    } else if (blockIdx.x < NN / 64 + NE / 64) {
        // ---------------- hidden branch ----------------
        unsigned short* eib = (unsigned short*)smem;
        float* kb1s = (float*)(smem + 17408);
        const int e0 = (blockIdx.x - NN / 64) * 64;
        if (t < KHD) kb1s[t] = kb1[t];
        for (int i = t; i < 64 * 32; i += 256) {
            int row = i >> 5, c4 = (i & 31) * 4;
            float4 xx = *(const float4*)(ei + (size_t)(e0 + row) * DE + c4);
            ushort4 o;
            o.x = f2bf(xx.x); o.y = f2bf(xx.y); o.z = f2bf(xx.z); o.w = f2bf(xx.w);
            *(ushort4*)(eib + row * EIS + c4) = o;
        }
        __syncthreads();
        f32x4 acc[2] = {zz, zz};
#pragma unroll
        for (int ks = 0; ks < 4; ++ks) {
            bf16x8 b = *(const bf16x8*)(eib + (w * 16 + le) * EIS + ks * 32 + g * 8);
#pragma unroll
            for (int jt = 0; jt < 2; ++jt) {
                bf16x8 a = *(const bf16x8*)(kw1b + (jt * 16 + le) * 128 + ks * 32 + g * 8);
                acc[jt] = __builtin_amdgcn_mfma_f32_16x16x32_bf16(a, b, acc[jt], 0, 0, 0);
            }
        }
        const int e = e0 + w * 16 + le;
#pragma unroll
        for (int jt = 0; jt < 2; ++jt) {
            int h = jt * 16 + g * 4;
            ushort4 o;
            o.x = f2bf(fmaxf(acc[jt][0] + kb1s[h + 0], 0.f));
            o.y = f2bf(fmaxf(acc[jt][1] + kb1s[h + 1], 0.f));
            o.z = f2bf(fmaxf(acc[jt][2] + kb1s[h + 2], 0.f));
            o.w = f2bf(fmaxf(acc[jt][3] + kb1s[h + 3], 0.f));
            *(ushort4*)(hid_b + (size_t)e * KHD + h) = o;
        }
    } else {
        // ---------------- pack branch (Wb2 / W0b / w2b) + zero cnt, cnt2 ----------------
        int idx = (blockIdx.x - (NN / 64 + NE / 64)) * 256 + t;
        if (idx < 33 * 4096) {
            int h = idx >> 12, r = idx & 4095;
            int half = r >> 11, wq = (r >> 9) & 3, ln = (r >> 3) & 63, k = r & 7;
            int gq = ln >> 4, lq = ln & 15;
            int row = wq * 16 + lq, col = half * 32 + gq * 8 + k;
            float v = (h < 32) ? kw2[(size_t)h * 4160 + 64 + (size_t)row * 64 + col]
                               : kb2[64 + row * 64 + col];
            Wb2[idx] = f2bf(v);
            return;
        }
        idx -= 33 * 4096;
        if (idx < 2048) { int j = idx >> 5, h = idx & 31; W0b[idx] = f2bf(kw2[(size_t)h * 4160 + j]); return; }
        idx -= 2048;
        if (idx < 16384) { int c = idx >> 6, k = idx & 63; w2b[idx] = f2bf(w2[(size_t)k * 256 + c]); return; }
        idx -= 16384;
        if (idx < NN) { cnt[idx] = 0; return; }
        idx -= NN;
        if (idx < NN) cnt2[idx] = 0;
    }
}

// ---------------- kernel D: fused bilinear via MFMA (128 edges/block, 4 waves) -----------
__global__ __launch_bounds__(256) void k_edge(
    const unsigned short* __restrict__ msgn_b,   // [NN][64]
    const unsigned short* __restrict__ hid_b,    // [NE][32]
    const int* __restrict__ elist, const float* __restrict__ eweight,
    int* __restrict__ cnt,
    const unsigned short* __restrict__ Wb2,      // [33][2][4][64*8] per-lane-linear
    const unsigned short* __restrict__ W0b,      // [64][32]
    const float* __restrict__ kb2,
    unsigned short* __restrict__ msg_out)        // [NN][DCAP][64] bf16 buckets, *eweight
{
    __shared__ __align__(16) float hids[128 * HS];
    __shared__ int eposs[128];
    const int t = threadIdx.x;
    const int w = t >> 6, le = t & 15, g = (t >> 4) & 3;
    const int lane = t & 63;
    const int e0 = blockIdx.x * 128;

    if (t < 128) {   // claim bucket slots for this block's edges
        int no = elist[(size_t)(e0 + t) * 2 + 1];
        eposs[t] = no * DCAP + atomicAdd(&cnt[no], 1);
    }

    for (int q = t; q < 1024; q += 256) {
        int e = q >> 3, h4 = (q & 7) * 4;
        ushort4 hh = *(const ushort4*)(hid_b + (size_t)(e0 + e) * KHD + h4);
        float4 f; f.x = bf2f(hh.x); f.y = bf2f(hh.y); f.z = bf2f(hh.z); f.w = bf2f(hh.w);
        *(float4*)(hids + e * HS + h4) = f;
    }
    if (t < 128) hids[t * HS + 32] = 1.0f;

    int eid[8];
#pragma unroll
    for (int nt = 0; nt < 8; ++nt) eid[nt] = e0 + nt * 16 + le;

    bf16x8 bm[8][2];
#pragma unroll
    for (int nt = 0; nt < 8; ++nt) {
        int ni = elist[(size_t)eid[nt] * 2];
#pragma unroll
        for (int ks = 0; ks < 2; ++ks)
            bm[nt][ks] = *(const bf16x8*)(msgn_b + (size_t)ni * HD + ks * 32 + g * 8);
    }

    const f32x4 zz = {0.f, 0.f, 0.f, 0.f};
    f32x4 acc[8];
    {   // r=0 block: A[j][h]=kw2[h,j], B=hid (bf16), K=32
        bf16x8 a0 = *(const bf16x8*)(W0b + (w * 16 + le) * KHD + g * 8);
#pragma unroll
        for (int nt = 0; nt < 8; ++nt) {
            bf16x8 hb = *(const bf16x8*)(hid_b + (size_t)eid[nt] * KHD + g * 8);
            acc[nt] = __builtin_amdgcn_mfma_f32_16x16x32_bf16(a0, hb, zz, 0, 0, 0);
        }
    }
    __syncthreads();

    int ep[8];
#pragma unroll
    for (int nt = 0; nt < 8; ++nt) ep[nt] = eposs[nt * 16 + le];

#pragma unroll 3
    for (int h = 0; h < 33; ++h) {
        float hv[8];
#pragma unroll
        for (int nt = 0; nt < 8; ++nt) hv[nt] = hids[(nt * 16 + le) * HS + h];
        const unsigned short* wrow = Wb2 + (size_t)h * 4096 + w * 512 + lane * 8;
        bf16x8 a0 = *(const bf16x8*)(wrow);
        bf16x8 a1 = *(const bf16x8*)(wrow + 2048);
#pragma unroll
        for (int nt = 0; nt < 8; ++nt) {
            f32x4 c = __builtin_amdgcn_mfma_f32_16x16x32_bf16(a0, bm[nt][0], zz, 0, 0, 0);
            c = __builtin_amdgcn_mfma_f32_16x16x32_bf16(a1, bm[nt][1], c, 0, 0, 0);
            acc[nt] += hv[nt] * c;
        }
    }

    const int j = w * 16 + g * 4;
    float4 kbv = *(const float4*)(kb2 + j);
#pragma unroll
    for (int nt = 0; nt < 8; ++nt) {
        float ew = eweight[eid[nt]];
        ushort4 o;
        o.x = f2bf((acc[nt][0] + kbv.x) * ew);
        o.y = f2bf((acc[nt][1] + kbv.y) * ew);
        o.z = f2bf((acc[nt][2] + kbv.z) * ew);
        o.w = f2bf((acc[nt][3] + kbv.w) * ew);
        *(ushort4*)(msg_out + (size_t)ep[nt] * HD + j) = o;
    }
}

// ---------------- kernel E: bucket segment-sum (bf16x8 vectorized) + BN + GEMM + BN -------
__global__ __launch_bounds__(256) void k_out(
    const unsigned short* __restrict__ msg_out,  // [NN][DCAP][64]
    const int* __restrict__ cnt,
    const unsigned short* __restrict__ w2b, const float* __restrict__ b2,
    const float* __restrict__ g_u, const float* __restrict__ be_u,
    const float* __restrict__ m_u, const float* __restrict__ v_u,
    const float* __restrict__ g_o, const float* __restrict__ be_o,
    const float* __restrict__ m_o, const float* __restrict__ v_o,
    float* __restrict__ out)
{
    __shared__ __align__(16) unsigned short utb[64 * UTS];
    __shared__ __align__(16) float sc_o[DOUT], sho2[DOUT], sc_u[HD], sh_u[HD];
    const int t = threadIdx.x;
    const int n0 = blockIdx.x * 64;
    {
        float s = g_o[t] * rsqrtf(v_o[t] + BN_EPS);
        sc_o[t] = s; sho2[t] = b2[t] * s + (be_o[t] - m_o[t] * s);
        if (t < HD) {
            float s2 = g_u[t] * rsqrtf(v_u[t] + BN_EPS);
            sc_u[t] = s2; sh_u[t] = be_u[t] - m_u[t] * s2;
        }
    }
    __syncthreads();
    {
        const int lane8 = t & 7, grp = t >> 3;   // grp 0..31
#pragma unroll
        for (int rr = 0; rr < 2; ++rr) {
            const int r = grp * 2 + rr;          // 0..63
            const int n = n0 + r;
            const int pc = cnt[n];
            const unsigned short* base = msg_out + (size_t)n * DCAP * HD + lane8 * 8;
            float a[8];
#pragma unroll
            for (int i = 0; i < 8; ++i) a[i] = 0.f;
            for (int p = 0; p < pc; ++p) {
                bf16x8 v = *(const bf16x8*)(base + (size_t)p * HD);
#pragma unroll
                for (int i = 0; i < 8; ++i) a[i] += bf2f((unsigned short)v[i]);
            }
            const int j = lane8 * 8;
            ushort4 o0, o1;
            o0.x = f2bf(fmaxf(fmaf(a[0], sc_u[j + 0], sh_u[j + 0]), 0.f));
            o0.y = f2bf(fmaxf(fmaf(a[1], sc_u[j + 1], sh_u[j + 1]), 0.f));
            o0.z = f2bf(fmaxf(fmaf(a[2], sc_u[j + 2], sh_u[j + 2]), 0.f));
            o0.w = f2bf(fmaxf(fmaf(a[3], sc_u[j + 3], sh_u[j + 3]), 0.f));
            o1.x = f2bf(fmaxf(fmaf(a[4], sc_u[j + 4], sh_u[j + 4]), 0.f));
            o1.y = f2bf(fmaxf(fmaf(a[5], sc_u[j + 5], sh_u[j + 5]), 0.f));
            o1.z = f2bf(fmaxf(fmaf(a[6], sc_u[j + 6], sh_u[j + 6]), 0.f));
            o1.w = f2bf(fmaxf(fmaf(a[7], sc_u[j + 7], sh_u[j + 7]), 0.f));
            *(ushort4*)(utb + r * UTS + j) = o0;
            *(ushort4*)(utb + r * UTS + j + 4) = o1;
        }
    }
    __syncthreads();
    const int w = t >> 6, le = t & 15, g = (t >> 4) & 3;
    const f32x4 zz = {0.f, 0.f, 0.f, 0.f};
    f32x4 acc[4][4];
#pragma unroll
    for (int jt = 0; jt < 4; ++jt)
#pragma unroll
        for (int nt = 0; nt < 4; ++nt) acc[jt][nt] = zz;
#pragma unroll
    for (int ks = 0; ks < 2; ++ks) {
        bf16x8 b[4];
#pragma unroll
        for (int nt = 0; nt < 4; ++nt)
            b[nt] = *(const bf16x8*)(utb + (nt * 16 + le) * UTS + ks * 32 + g * 8);
#pragma unroll
        for (int jt = 0; jt < 4; ++jt) {
            bf16x8 a = *(const bf16x8*)(w2b + (size_t)(w * 64 + jt * 16 + le) * HD + ks * 32 + g * 8);
#pragma unroll
            for (int nt = 0; nt < 4; ++nt)
                acc[jt][nt] = __builtin_amdgcn_mfma_f32_16x16x32_bf16(a, b[nt], acc[jt][nt], 0, 0, 0);
        }
    }
#pragma unroll
    for (int jt = 0; jt < 4; ++jt) {
        int c = w * 64 + jt * 16 + g * 4;
        float4 sc = *(const float4*)(sc_o + c);
        float4 sh = *(const float4*)(sho2 + c);
#pragma unroll
        for (int nt = 0; nt < 4; ++nt) {
            int n = n0 + nt * 16 + le;
            float4 o;
            o.x = fmaf(acc[jt][nt][0], sc.x, sh.x);
            o.y = fmaf(acc[jt][nt][1], sc.y, sh.y);
            o.z = fmaf(acc[jt][nt][2], sc.z, sh.z);
            o.w = fmaf(acc[jt][nt][3], sc.w, sh.w);
            *(float4*)(out + (size_t)n * DOUT + c) = o;
        }
    }
}

extern "C" void kernel_launch(void* const* d_in, const int* in_sizes, int n_in,
                              void* d_out, int out_size, void* d_ws, size_t ws_size,
                              hipStream_t stream)
{
    (void)in_sizes; (void)n_in; (void)out_size; (void)ws_size;
    const float* x    = (const float*)d_in[0];
    const float* ei   = (const float*)d_in[1];
    const int*   el   = (const int*)  d_in[2];
    const float* ew   = (const float*)d_in[3];
    const float* w1   = (const float*)d_in[4];
    const float* b1   = (const float*)d_in[5];
    const float* kw1  = (const float*)d_in[6];
    const float* kb1  = (const float*)d_in[7];
    const float* kw2  = (const float*)d_in[8];
    const float* kb2  = (const float*)d_in[9];
    const float* w2   = (const float*)d_in[10];
    const float* b2   = (const float*)d_in[11];
    const float* g_in = (const float*)d_in[12], *be_in = (const float*)d_in[13];
    const float* m_in = (const float*)d_in[14], *v_in  = (const float*)d_in[15];
    const float* g_m  = (const float*)d_in[16], *be_m  = (const float*)d_in[17];
    const float* m_m  = (const float*)d_in[18], *v_m   = (const float*)d_in[19];
    const float* g_u  = (const float*)d_in[20], *be_u  = (const float*)d_in[21];
    const float* m_u  = (const float*)d_in[22], *v_u   = (const float*)d_in[23];
    const float* g_o  = (const float*)d_in[24], *be_o  = (const float*)d_in[25];
    const float* m_o  = (const float*)d_in[26], *v_o   = (const float*)d_in[27];

    char* wsb = (char*)d_ws;
    size_t off = 0;
    auto alloc = [&](size_t bytes) -> void* {
        void* p = wsb + off; off += (bytes + 255) & ~(size_t)255; return p;
    };
    unsigned short* msgn_b  = (unsigned short*)alloc((size_t)NN * HD * 2);
    unsigned short* hid_b   = (unsigned short*)alloc((size_t)NE * KHD * 2);
    unsigned short* Wb2     = (unsigned short*)alloc((size_t)33 * 4096 * 2);
    unsigned short* W0b     = (unsigned short*)alloc((size_t)64 * KHD * 2);
    unsigned short* w1b     = (unsigned short*)alloc((size_t)HD * DIN * 2);
    unsigned short* kw1b    = (unsigned short*)alloc((size_t)KHD * DE * 2);
    unsigned short* w2b     = (unsigned short*)alloc((size_t)DOUT * HD * 2);
    int* cnt  = (int*)alloc((size_t)NN * 4);
    int* cnt2 = (int*)alloc((size_t)NN * 4);
    unsigned short* msg_out = (unsigned short*)alloc((size_t)NN * DCAP * HD * 2);

    hipLaunchKernelGGL(k_prepw, dim3(80), dim3(256), 0, stream, w1, kw1, w1b, kw1b);
    hipLaunchKernelGGL(k_mh, dim3(NN / 64 + NE / 64 + 726), dim3(256), 0, stream,
                       x, w1b, b1, g_in, be_in, m_in, v_in, g_m, be_m, m_m, v_m, msgn_b,
                       ei, kw1b, kb1, hid_b, kw2, kb2, w2, Wb2, W0b, w2b, cnt, cnt2);
    // DIAGNOSTIC: k_edge twice. First uses throwaway cnt2 (same slot ranges, same values);
    // second (real) overwrites every slot it assigns -> final msg_out identical.
    hipLaunchKernelGGL(k_edge, dim3(NE / 128), dim3(256), 0, stream,
                       msgn_b, hid_b, el, ew, cnt2, Wb2, W0b, kb2, msg_out);
    hipLaunchKernelGGL(k_edge, dim3(NE / 128), dim3(256), 0, stream,
                       msgn_b, hid_b, el, ew, cnt, Wb2, W0b, kb2, msg_out);
    hipLaunchKernelGGL(k_out, dim3(NN / 64), dim3(256), 0, stream,
                       msg_out, cnt, w2b, b2, g_u, be_u, m_u, v_u,
                       g_o, be_o, m_o, v_o, (float*)d_out);
}

// Round 21
// 77.886 us; speedup vs baseline: 1.3118x; 1.3118x over previous
//
#include <hip/hip_runtime.h>

#define NN   16000
#define NE   64000
#define DIN  256
#define HD   64
#define DOUT 256
#define DE   128
#define KHD  32
#define DCAP 32
#define BN_EPS 1e-5f
#define LNS 264
#define EIS 136
#define HS  36
#define UTS 72

typedef __attribute__((ext_vector_type(8))) short bf16x8;
typedef __attribute__((ext_vector_type(4))) float f32x4;

__device__ __forceinline__ unsigned short f2bf(float f) {
    unsigned int u = __float_as_uint(f);
    u += 0x7fff + ((u >> 16) & 1);
    return (unsigned short)(u >> 16);
}
__device__ __forceinline__ float bf2f(unsigned short s) {
    return __uint_as_float(((unsigned int)s) << 16);
}

// ---------------- kernel PW: pack only w1b/kw1b (needed by k_mh) -------------------------
__global__ __launch_bounds__(256) void k_prepw(
    const float* __restrict__ w1, const float* __restrict__ kw1,
    unsigned short* __restrict__ w1b, unsigned short* __restrict__ kw1b)
{
    int idx = blockIdx.x * 256 + threadIdx.x;
    if (idx < 16384) { int j = idx >> 8, k = idx & 255; w1b[idx] = f2bf(w1[(size_t)k * 64 + j]); return; }
    idx -= 16384;
    if (idx < 4096) { int h = idx >> 7, k = idx & 127; kw1b[idx] = f2bf(kw1[(size_t)k * 32 + h]); }
}

// ---------------- kernel MH: msgn (0..249) | hidden (250..1249) | pack+cntzero (1250..) --
__global__ __launch_bounds__(256) void k_mh(
    const float* __restrict__ x, const unsigned short* __restrict__ w1b,
    const float* __restrict__ b1,
    const float* __restrict__ g_in, const float* __restrict__ be_in,
    const float* __restrict__ m_in, const float* __restrict__ v_in,
    const float* __restrict__ g_m, const float* __restrict__ be_m,
    const float* __restrict__ m_m, const float* __restrict__ v_m,
    unsigned short* __restrict__ msgn_b,
    const float* __restrict__ ei, const unsigned short* __restrict__ kw1b,
    const float* __restrict__ kb1, unsigned short* __restrict__ hid_b,
    const float* __restrict__ kw2, const float* __restrict__ kb2,
    const float* __restrict__ w2,
    unsigned short* __restrict__ Wb2, unsigned short* __restrict__ W0b,
    unsigned short* __restrict__ w2b, int* __restrict__ cnt)
{
    __shared__ __align__(16) unsigned char smem[36608];
    const int t = threadIdx.x;
    const int w = t >> 6, le = t & 15, g = (t >> 4) & 3;
    const f32x4 zz = {0.f, 0.f, 0.f, 0.f};

    if (blockIdx.x < NN / 64) {
        // ---------------- msgn branch ----------------
        unsigned short* lnb = (unsigned short*)smem;
        float* sc_in = (float*)(smem + 33792);
        float* sh_in = (float*)(smem + 34816);
        float* sc_m  = (float*)(smem + 35840);
        float* shm2  = (float*)(smem + 36096);
        const int n0 = blockIdx.x * 64;
        {
            float s = g_in[t] * rsqrtf(v_in[t] + BN_EPS);
            sc_in[t] = s; sh_in[t] = be_in[t] - m_in[t] * s;
            if (t < HD) {
                float s2 = g_m[t] * rsqrtf(v_m[t] + BN_EPS);
                sc_m[t] = s2; shm2[t] = b1[t] * s2 + (be_m[t] - m_m[t] * s2);
            }
        }
        __syncthreads();
        for (int i = t; i < 64 * 64; i += 256) {
            int row = i >> 6, c4 = (i & 63) * 4;
            float4 xx = *(const float4*)(x + (size_t)(n0 + row) * DIN + c4);
            float4 sc = *(const float4*)(sc_in + c4);
            float4 sh = *(const float4*)(sh_in + c4);
            ushort4 o;
            o.x = f2bf(fmaxf(fmaf(xx.x, sc.x, sh.x), 0.f));
            o.y = f2bf(fmaxf(fmaf(xx.y, sc.y, sh.y), 0.f));
            o.z = f2bf(fmaxf(fmaf(xx.z, sc.z, sh.z), 0.f));
            o.w = f2bf(fmaxf(fmaf(xx.w, sc.w, sh.w), 0.f));
            *(ushort4*)(lnb + row * LNS + c4) = o;
        }
        __syncthreads();
        f32x4 acc[4] = {zz, zz, zz, zz};
#pragma unroll
        for (int ks = 0; ks < 8; ++ks) {
            bf16x8 b = *(const bf16x8*)(lnb + (w * 16 + le) * LNS + ks * 32 + g * 8);
#pragma unroll
            for (int jt = 0; jt < 4; ++jt) {
                bf16x8 a = *(const bf16x8*)(w1b + (jt * 16 + le) * 256 + ks * 32 + g * 8);
                acc[jt] = __builtin_amdgcn_mfma_f32_16x16x32_bf16(a, b, acc[jt], 0, 0, 0);
            }
        }
        const int n = n0 + w * 16 + le;
#pragma unroll
        for (int jt = 0; jt < 4; ++jt) {
            int j = jt * 16 + g * 4;
            float4 sc = *(const float4*)(sc_m + j);
            float4 sh = *(const float4*)(shm2 + j);
            ushort4 o;
            o.x = f2bf(fmaxf(fmaf(acc[jt][0], sc.x, sh.x), 0.f));
            o.y = f2bf(fmaxf(fmaf(acc[jt][1], sc.y, sh.y), 0.f));
            o.z = f2bf(fmaxf(fmaf(acc[jt][2], sc.z, sh.z), 0.f));
            o.w = f2bf(fmaxf(fmaf(acc[jt][3], sc.w, sh.w), 0.f));
            *(ushort4*)(msgn_b + (size_t)n * HD + j) = o;
        }
    } else if (blockIdx.x < NN / 64 + NE / 64) {
        // ---------------- hidden branch ----------------
        unsigned short* eib = (unsigned short*)smem;
        float* kb1s = (float*)(smem + 17408);
        const int e0 = (blockIdx.x - NN / 64) * 64;
        if (t < KHD) kb1s[t] = kb1[t];
        for (int i = t; i < 64 * 32; i += 256) {
            int row = i >> 5, c4 = (i & 31) * 4;
            float4 xx = *(const float4*)(ei + (size_t)(e0 + row) * DE + c4);
            ushort4 o;
            o.x = f2bf(xx.x); o.y = f2bf(xx.y); o.z = f2bf(xx.z); o.w = f2bf(xx.w);
            *(ushort4*)(eib + row * EIS + c4) = o;
        }
        __syncthreads();
        f32x4 acc[2] = {zz, zz};
#pragma unroll
        for (int ks = 0; ks < 4; ++ks) {
            bf16x8 b = *(const bf16x8*)(eib + (w * 16 + le) * EIS + ks * 32 + g * 8);
#pragma unroll
            for (int jt = 0; jt < 2; ++jt) {
                bf16x8 a = *(const bf16x8*)(kw1b + (jt * 16 + le) * 128 + ks * 32 + g * 8);
                acc[jt] = __builtin_amdgcn_mfma_f32_16x16x32_bf16(a, b, acc[jt], 0, 0, 0);
            }
        }
        const int e = e0 + w * 16 + le;
#pragma unroll
        for (int jt = 0; jt < 2; ++jt) {
            int h = jt * 16 + g * 4;
            ushort4 o;
            o.x = f2bf(fmaxf(acc[jt][0] + kb1s[h + 0], 0.f));
            o.y = f2bf(fmaxf(acc[jt][1] + kb1s[h + 1], 0.f));
            o.z = f2bf(fmaxf(acc[jt][2] + kb1s[h + 2], 0.f));
            o.w = f2bf(fmaxf(acc[jt][3] + kb1s[h + 3], 0.f));
            *(ushort4*)(hid_b + (size_t)e * KHD + h) = o;
        }
    } else {
        // ---------------- pack branch (Wb2 / W0b / w2b) + cnt zero ----------------
        int idx = (blockIdx.x - (NN / 64 + NE / 64)) * 256 + t;
        if (idx < 33 * 4096) {
            int h = idx >> 12, r = idx & 4095;
            int half = r >> 11, wq = (r >> 9) & 3, ln = (r >> 3) & 63, k = r & 7;
            int gq = ln >> 4, lq = ln & 15;
            int row = wq * 16 + lq, col = half * 32 + gq * 8 + k;
            float v = (h < 32) ? kw2[(size_t)h * 4160 + 64 + (size_t)row * 64 + col]
                               : kb2[64 + row * 64 + col];
            Wb2[idx] = f2bf(v);
            return;
        }
        idx -= 33 * 4096;
        if (idx < 2048) { int j = idx >> 5, h = idx & 31; W0b[idx] = f2bf(kw2[(size_t)h * 4160 + j]); return; }
        idx -= 2048;
        if (idx < 16384) { int c = idx >> 6, k = idx & 63; w2b[idx] = f2bf(w2[(size_t)k * 256 + c]); return; }
        idx -= 16384;
        if (idx < NN) cnt[idx] = 0;
    }
}

// ---------------- kernel D: fused bilinear via MFMA, LDS-chunk-staged weights ------------
// Per chunk: all 256 threads stage 4 h-rows (32KB) of Wb2 into LDS in parallel (coalesced
// bf16x8 copies), barrier, then 4 iters of pure-LDS fragment reads + MFMA. h=32 is a
// direct-from-global tail. Same arithmetic order as the proven kernel.
__global__ __launch_bounds__(256) void k_edge(
    const unsigned short* __restrict__ msgn_b,   // [NN][64]
    const unsigned short* __restrict__ hid_b,    // [NE][32]
    const int* __restrict__ elist, const float* __restrict__ eweight,
    int* __restrict__ cnt,
    const unsigned short* __restrict__ Wb2,      // [33][2][4][64*8] per-lane-linear
    const unsigned short* __restrict__ W0b,      // [64][32]
    const float* __restrict__ kb2,
    unsigned short* __restrict__ msg_out)        // [NN][DCAP][64] bf16 buckets, *eweight
{
    __shared__ __align__(16) float hids[128 * HS];          // 18432 B
    __shared__ int eposs[128];                              //   512 B
    __shared__ __align__(16) unsigned short wch[4 * 4096];  // 32768 B
    const int t = threadIdx.x;
    const int w = t >> 6, le = t & 15, g = (t >> 4) & 3;
    const int lane = t & 63;
    const int e0 = blockIdx.x * 128;

    if (t < 128) {   // claim bucket slots for this block's edges
        int no = elist[(size_t)(e0 + t) * 2 + 1];
        eposs[t] = no * DCAP + atomicAdd(&cnt[no], 1);
    }

    for (int q = t; q < 1024; q += 256) {
        int e = q >> 3, h4 = (q & 7) * 4;
        ushort4 hh = *(const ushort4*)(hid_b + (size_t)(e0 + e) * KHD + h4);
        float4 f; f.x = bf2f(hh.x); f.y = bf2f(hh.y); f.z = bf2f(hh.z); f.w = bf2f(hh.w);
        *(float4*)(hids + e * HS + h4) = f;
    }
    if (t < 128) hids[t * HS + 32] = 1.0f;

    int eid[8];
#pragma unroll
    for (int nt = 0; nt < 8; ++nt) eid[nt] = e0 + nt * 16 + le;

    bf16x8 bm[8][2];
#pragma unroll
    for (int nt = 0; nt < 8; ++nt) {
        int ni = elist[(size_t)eid[nt] * 2];
#pragma unroll
        for (int ks = 0; ks < 2; ++ks)
            bm[nt][ks] = *(const bf16x8*)(msgn_b + (size_t)ni * HD + ks * 32 + g * 8);
    }

    const f32x4 zz = {0.f, 0.f, 0.f, 0.f};
    f32x4 acc[8];
    {   // r=0 block: A[j][h]=kw2[h,j], B=hid (bf16), K=32
        bf16x8 a0 = *(const bf16x8*)(W0b + (w * 16 + le) * KHD + g * 8);
#pragma unroll
        for (int nt = 0; nt < 8; ++nt) {
            bf16x8 hb = *(const bf16x8*)(hid_b + (size_t)eid[nt] * KHD + g * 8);
            acc[nt] = __builtin_amdgcn_mfma_f32_16x16x32_bf16(a0, hb, zz, 0, 0, 0);
        }
    }
    __syncthreads();   // hids + eposs visible

    int ep[8];
#pragma unroll
    for (int nt = 0; nt < 8; ++nt) ep[nt] = eposs[nt * 16 + le];

    // ---- h = 0..31 in 8 chunks of 4 rows, LDS-staged ----
    for (int c = 0; c < 8; ++c) {
        const unsigned short* src = Wb2 + (size_t)(c * 4) * 4096;
#pragma unroll
        for (int q = 0; q < 8; ++q)
            *(bf16x8*)(wch + q * 2048 + t * 8) = *(const bf16x8*)(src + q * 2048 + t * 8);
        __syncthreads();
#pragma unroll
        for (int r = 0; r < 4; ++r) {
            const int h = c * 4 + r;
            float hv[8];
#pragma unroll
            for (int nt = 0; nt < 8; ++nt) hv[nt] = hids[(nt * 16 + le) * HS + h];
            const unsigned short* wrow = wch + r * 4096 + w * 512 + lane * 8;
            bf16x8 a0 = *(const bf16x8*)(wrow);
            bf16x8 a1 = *(const bf16x8*)(wrow + 2048);
#pragma unroll
            for (int nt = 0; nt < 8; ++nt) {
                f32x4 cc = __builtin_amdgcn_mfma_f32_16x16x32_bf16(a0, bm[nt][0], zz, 0, 0, 0);
                cc = __builtin_amdgcn_mfma_f32_16x16x32_bf16(a1, bm[nt][1], cc, 0, 0, 0);
                acc[nt] += hv[nt] * cc;
            }
        }
        __syncthreads();   // protect wch before next chunk's staging
    }
    // ---- h = 32 tail (bias row), direct from global ----
    {
        float hv[8];
#pragma unroll
        for (int nt = 0; nt < 8; ++nt) hv[nt] = hids[(nt * 16 + le) * HS + 32];
        const unsigned short* wrow = Wb2 + (size_t)32 * 4096 + w * 512 + lane * 8;
        bf16x8 a0 = *(const bf16x8*)(wrow);
        bf16x8 a1 = *(const bf16x8*)(wrow + 2048);
#pragma unroll
        for (int nt = 0; nt < 8; ++nt) {
            f32x4 cc = __builtin_amdgcn_mfma_f32_16x16x32_bf16(a0, bm[nt][0], zz, 0, 0, 0);
            cc = __builtin_amdgcn_mfma_f32_16x16x32_bf16(a1, bm[nt][1], cc, 0, 0, 0);
            acc[nt] += hv[nt] * cc;
        }
    }

    const int j = w * 16 + g * 4;
    float4 kbv = *(const float4*)(kb2 + j);
#pragma unroll
    for (int nt = 0; nt < 8; ++nt) {
        float ew = eweight[eid[nt]];
        ushort4 o;
        o.x = f2bf((acc[nt][0] + kbv.x) * ew);
        o.y = f2bf((acc[nt][1] + kbv.y) * ew);
        o.z = f2bf((acc[nt][2] + kbv.z) * ew);
        o.w = f2bf((acc[nt][3] + kbv.w) * ew);
        *(ushort4*)(msg_out + (size_t)ep[nt] * HD + j) = o;
    }
}

// ---------------- kernel E: bucket segment-sum (bf16x8 vectorized) + BN + GEMM + BN -------
__global__ __launch_bounds__(256) void k_out(
    const unsigned short* __restrict__ msg_out,  // [NN][DCAP][64]
    const int* __restrict__ cnt,
    const unsigned short* __restrict__ w2b, const float* __restrict__ b2,
    const float* __restrict__ g_u, const float* __restrict__ be_u,
    const float* __restrict__ m_u, const float* __restrict__ v_u,
    const float* __restrict__ g_o, const float* __restrict__ be_o,
    const float* __restrict__ m_o, const float* __restrict__ v_o,
    float* __restrict__ out)
{
    __shared__ __align__(16) unsigned short utb[64 * UTS];
    __shared__ __align__(16) float sc_o[DOUT], sho2[DOUT], sc_u[HD], sh_u[HD];
    const int t = threadIdx.x;
    const int n0 = blockIdx.x * 64;
    {
        float s = g_o[t] * rsqrtf(v_o[t] + BN_EPS);
        sc_o[t] = s; sho2[t] = b2[t] * s + (be_o[t] - m_o[t] * s);
        if (t < HD) {
            float s2 = g_u[t] * rsqrtf(v_u[t] + BN_EPS);
            sc_u[t] = s2; sh_u[t] = be_u[t] - m_u[t] * s2;
        }
    }
    __syncthreads();
    {
        const int lane8 = t & 7, grp = t >> 3;   // grp 0..31
#pragma unroll
        for (int rr = 0; rr < 2; ++rr) {
            const int r = grp * 2 + rr;          // 0..63
            const int n = n0 + r;
            const int pc = cnt[n];
            const unsigned short* base = msg_out + (size_t)n * DCAP * HD + lane8 * 8;
            float a[8];
#pragma unroll
            for (int i = 0; i < 8; ++i) a[i] = 0.f;
            for (int p = 0; p < pc; ++p) {
                bf16x8 v = *(const bf16x8*)(base + (size_t)p * HD);
#pragma unroll
                for (int i = 0; i < 8; ++i) a[i] += bf2f((unsigned short)v[i]);
            }
            const int j = lane8 * 8;
            ushort4 o0, o1;
            o0.x = f2bf(fmaxf(fmaf(a[0], sc_u[j + 0], sh_u[j + 0]), 0.f));
            o0.y = f2bf(fmaxf(fmaf(a[1], sc_u[j + 1], sh_u[j + 1]), 0.f));
            o0.z = f2bf(fmaxf(fmaf(a[2], sc_u[j + 2], sh_u[j + 2]), 0.f));
            o0.w = f2bf(fmaxf(fmaf(a[3], sc_u[j + 3], sh_u[j + 3]), 0.f));
            o1.x = f2bf(fmaxf(fmaf(a[4], sc_u[j + 4], sh_u[j + 4]), 0.f));
            o1.y = f2bf(fmaxf(fmaf(a[5], sc_u[j + 5], sh_u[j + 5]), 0.f));
            o1.z = f2bf(fmaxf(fmaf(a[6], sc_u[j + 6], sh_u[j + 6]), 0.f));
            o1.w = f2bf(fmaxf(fmaf(a[7], sc_u[j + 7], sh_u[j + 7]), 0.f));
            *(ushort4*)(utb + r * UTS + j) = o0;
            *(ushort4*)(utb + r * UTS + j + 4) = o1;
        }
    }
    __syncthreads();
    const int w = t >> 6, le = t & 15, g = (t >> 4) & 3;
    const f32x4 zz = {0.f, 0.f, 0.f, 0.f};
    f32x4 acc[4][4];
#pragma unroll
    for (int jt = 0; jt < 4; ++jt)
#pragma unroll
        for (int nt = 0; nt < 4; ++nt) acc[jt][nt] = zz;
#pragma unroll
    for (int ks = 0; ks < 2; ++ks) {
        bf16x8 b[4];
#pragma unroll
        for (int nt = 0; nt < 4; ++nt)
            b[nt] = *(const bf16x8*)(utb + (nt * 16 + le) * UTS + ks * 32 + g * 8);
#pragma unroll
        for (int jt = 0; jt < 4; ++jt) {
            bf16x8 a = *(const bf16x8*)(w2b + (size_t)(w * 64 + jt * 16 + le) * HD + ks * 32 + g * 8);
#pragma unroll
            for (int nt = 0; nt < 4; ++nt)
                acc[jt][nt] = __builtin_amdgcn_mfma_f32_16x16x32_bf16(a, b[nt], acc[jt][nt], 0, 0, 0);
        }
    }
#pragma unroll
    for (int jt = 0; jt < 4; ++jt) {
        int c = w * 64 + jt * 16 + g * 4;
        float4 sc = *(const float4*)(sc_o + c);
        float4 sh = *(const float4*)(sho2 + c);
#pragma unroll
        for (int nt = 0; nt < 4; ++nt) {
            int n = n0 + nt * 16 + le;
            float4 o;
            o.x = fmaf(acc[jt][nt][0], sc.x, sh.x);
            o.y = fmaf(acc[jt][nt][1], sc.y, sh.y);
            o.z = fmaf(acc[jt][nt][2], sc.z, sh.z);
            o.w = fmaf(acc[jt][nt][3], sc.w, sh.w);
            *(float4*)(out + (size_t)n * DOUT + c) = o;
        }
    }
}

extern "C" void kernel_launch(void* const* d_in, const int* in_sizes, int n_in,
                              void* d_out, int out_size, void* d_ws, size_t ws_size,
                              hipStream_t stream)
{
    (void)in_sizes; (void)n_in; (void)out_size; (void)ws_size;
    const float* x    = (const float*)d_in[0];
    const float* ei   = (const float*)d_in[1];
    const int*   el   = (const int*)  d_in[2];
    const float* ew   = (const float*)d_in[3];
    const float* w1   = (const float*)d_in[4];
    const float* b1   = (const float*)d_in[5];
    const float* kw1  = (const float*)d_in[6];
    const float* kb1  = (const float*)d_in[7];
    const float* kw2  = (const float*)d_in[8];
    const float* kb2  = (const float*)d_in[9];
    const float* w2   = (const float*)d_in[10];
    const float* b2   = (const float*)d_in[11];
    const float* g_in = (const float*)d_in[12], *be_in = (const float*)d_in[13];
    const float* m_in = (const float*)d_in[14], *v_in  = (const float*)d_in[15];
    const float* g_m  = (const float*)d_in[16], *be_m  = (const float*)d_in[17];
    const float* m_m  = (const float*)d_in[18], *v_m   = (const float*)d_in[19];
    const float* g_u  = (const float*)d_in[20], *be_u  = (const float*)d_in[21];
    const float* m_u  = (const float*)d_in[22], *v_u   = (const float*)d_in[23];
    const float* g_o  = (const float*)d_in[24], *be_o  = (const float*)d_in[25];
    const float* m_o  = (const float*)d_in[26], *v_o   = (const float*)d_in[27];

    char* wsb = (char*)d_ws;
    size_t off = 0;
    auto alloc = [&](size_t bytes) -> void* {
        void* p = wsb + off; off += (bytes + 255) & ~(size_t)255; return p;
    };
    unsigned short* msgn_b  = (unsigned short*)alloc((size_t)NN * HD * 2);
    unsigned short* hid_b   = (unsigned short*)alloc((size_t)NE * KHD * 2);
    unsigned short* Wb2     = (unsigned short*)alloc((size_t)33 * 4096 * 2);
    unsigned short* W0b     = (unsigned short*)alloc((size_t)64 * KHD * 2);
    unsigned short* w1b     = (unsigned short*)alloc((size_t)HD * DIN * 2);
    unsigned short* kw1b    = (unsigned short*)alloc((size_t)KHD * DE * 2);
    unsigned short* w2b     = (unsigned short*)alloc((size_t)DOUT * HD * 2);
    int* cnt = (int*)alloc((size_t)NN * 4);
    unsigned short* msg_out = (unsigned short*)alloc((size_t)NN * DCAP * HD * 2);

    hipLaunchKernelGGL(k_prepw, dim3(80), dim3(256), 0, stream, w1, kw1, w1b, kw1b);
    hipLaunchKernelGGL(k_mh, dim3(NN / 64 + NE / 64 + 663), dim3(256), 0, stream,
                       x, w1b, b1, g_in, be_in, m_in, v_in, g_m, be_m, m_m, v_m, msgn_b,
                       ei, kw1b, kb1, hid_b, kw2, kb2, w2, Wb2, W0b, w2b, cnt);
    hipLaunchKernelGGL(k_edge, dim3(NE / 128), dim3(256), 0, stream,
                       msgn_b, hid_b, el, ew, cnt, Wb2, W0b, kb2, msg_out);
    hipLaunchKernelGGL(k_out, dim3(NN / 64), dim3(256), 0, stream,
                       msg_out, cnt, w2b, b2, g_u, be_u, m_u, v_u,
                       g_o, be_o, m_o, v_o, (float*)d_out);
}

// Round 22
// 71.742 us; speedup vs baseline: 1.4242x; 1.0856x over previous
//
#include <hip/hip_runtime.h>

#define NN   16000
#define NE   64000
#define DIN  256
#define HD   64
#define DOUT 256
#define DE   128
#define KHD  32
#define DCAP 32
#define BN_EPS 1e-5f
#define LNS 264
#define EIS 136
#define HS  36
#define UTS 72

typedef __attribute__((ext_vector_type(8))) short bf16x8;
typedef __attribute__((ext_vector_type(4))) float f32x4;

__device__ __forceinline__ unsigned short f2bf(float f) {
    unsigned int u = __float_as_uint(f);
    u += 0x7fff + ((u >> 16) & 1);
    return (unsigned short)(u >> 16);
}
__device__ __forceinline__ float bf2f(unsigned short s) {
    return __uint_as_float(((unsigned int)s) << 16);
}

// ---------------- kernel PW: pack only w1b/kw1b (needed by k_mh) -------------------------
__global__ __launch_bounds__(256) void k_prepw(
    const float* __restrict__ w1, const float* __restrict__ kw1,
    unsigned short* __restrict__ w1b, unsigned short* __restrict__ kw1b)
{
    int idx = blockIdx.x * 256 + threadIdx.x;
    if (idx < 16384) { int j = idx >> 8, k = idx & 255; w1b[idx] = f2bf(w1[(size_t)k * 64 + j]); return; }
    idx -= 16384;
    if (idx < 4096) { int h = idx >> 7, k = idx & 127; kw1b[idx] = f2bf(kw1[(size_t)k * 32 + h]); }
}

// ---------------- kernel MH: msgn (0..249) | hidden (250..1249) | pack+cntzero (1250..) --
__global__ __launch_bounds__(256) void k_mh(
    const float* __restrict__ x, const unsigned short* __restrict__ w1b,
    const float* __restrict__ b1,
    const float* __restrict__ g_in, const float* __restrict__ be_in,
    const float* __restrict__ m_in, const float* __restrict__ v_in,
    const float* __restrict__ g_m, const float* __restrict__ be_m,
    const float* __restrict__ m_m, const float* __restrict__ v_m,
    unsigned short* __restrict__ msgn_b,
    const float* __restrict__ ei, const unsigned short* __restrict__ kw1b,
    const float* __restrict__ kb1, unsigned short* __restrict__ hid_b,
    const float* __restrict__ kw2, const float* __restrict__ kb2,
    const float* __restrict__ w2,
    unsigned short* __restrict__ Wb2, unsigned short* __restrict__ W0b,
    unsigned short* __restrict__ w2b, int* __restrict__ cnt)
{
    __shared__ __align__(16) unsigned char smem[36608];
    const int t = threadIdx.x;
    const int w = t >> 6, le = t & 15, g = (t >> 4) & 3;
    const f32x4 zz = {0.f, 0.f, 0.f, 0.f};

    if (blockIdx.x < NN / 64) {
        // ---------------- msgn branch ----------------
        unsigned short* lnb = (unsigned short*)smem;
        float* sc_in = (float*)(smem + 33792);
        float* sh_in = (float*)(smem + 34816);
        float* sc_m  = (float*)(smem + 35840);
        float* shm2  = (float*)(smem + 36096);
        const int n0 = blockIdx.x * 64;
        {
            float s = g_in[t] * rsqrtf(v_in[t] + BN_EPS);
            sc_in[t] = s; sh_in[t] = be_in[t] - m_in[t] * s;
            if (t < HD) {
                float s2 = g_m[t] * rsqrtf(v_m[t] + BN_EPS);
                sc_m[t] = s2; shm2[t] = b1[t] * s2 + (be_m[t] - m_m[t] * s2);
            }
        }
        __syncthreads();
        for (int i = t; i < 64 * 64; i += 256) {
            int row = i >> 6, c4 = (i & 63) * 4;
            float4 xx = *(const float4*)(x + (size_t)(n0 + row) * DIN + c4);
            float4 sc = *(const float4*)(sc_in + c4);
            float4 sh = *(const float4*)(sh_in + c4);
            ushort4 o;
            o.x = f2bf(fmaxf(fmaf(xx.x, sc.x, sh.x), 0.f));
            o.y = f2bf(fmaxf(fmaf(xx.y, sc.y, sh.y), 0.f));
            o.z = f2bf(fmaxf(fmaf(xx.z, sc.z, sh.z), 0.f));
            o.w = f2bf(fmaxf(fmaf(xx.w, sc.w, sh.w), 0.f));
            *(ushort4*)(lnb + row * LNS + c4) = o;
        }
        __syncthreads();
        f32x4 acc[4] = {zz, zz, zz, zz};
#pragma unroll
        for (int ks = 0; ks < 8; ++ks) {
            bf16x8 b = *(const bf16x8*)(lnb + (w * 16 + le) * LNS + ks * 32 + g * 8);
#pragma unroll
            for (int jt = 0; jt < 4; ++jt) {
                bf16x8 a = *(const bf16x8*)(w1b + (jt * 16 + le) * 256 + ks * 32 + g * 8);
                acc[jt] = __builtin_amdgcn_mfma_f32_16x16x32_bf16(a, b, acc[jt], 0, 0, 0);
            }
        }
        const int n = n0 + w * 16 + le;
#pragma unroll
        for (int jt = 0; jt < 4; ++jt) {
            int j = jt * 16 + g * 4;
            float4 sc = *(const float4*)(sc_m + j);
            float4 sh = *(const float4*)(shm2 + j);
            ushort4 o;
            o.x = f2bf(fmaxf(fmaf(acc[jt][0], sc.x, sh.x), 0.f));
            o.y = f2bf(fmaxf(fmaf(acc[jt][1], sc.y, sh.y), 0.f));
            o.z = f2bf(fmaxf(fmaf(acc[jt][2], sc.z, sh.z), 0.f));
            o.w = f2bf(fmaxf(fmaf(acc[jt][3], sc.w, sh.w), 0.f));
            *(ushort4*)(msgn_b + (size_t)n * HD + j) = o;
        }
    } else if (blockIdx.x < NN / 64 + NE / 64) {
        // ---------------- hidden branch ----------------
        unsigned short* eib = (unsigned short*)smem;
        float* kb1s = (float*)(smem + 17408);
        const int e0 = (blockIdx.x - NN / 64) * 64;
        if (t < KHD) kb1s[t] = kb1[t];
        for (int i = t; i < 64 * 32; i += 256) {
            int row = i >> 5, c4 = (i & 31) * 4;
            float4 xx = *(const float4*)(ei + (size_t)(e0 + row) * DE + c4);
            ushort4 o;
            o.x = f2bf(xx.x); o.y = f2bf(xx.y); o.z = f2bf(xx.z); o.w = f2bf(xx.w);
            *(ushort4*)(eib + row * EIS + c4) = o;
        }
        __syncthreads();
        f32x4 acc[2] = {zz, zz};
#pragma unroll
        for (int ks = 0; ks < 4; ++ks) {
            bf16x8 b = *(const bf16x8*)(eib + (w * 16 + le) * EIS + ks * 32 + g * 8);
#pragma unroll
            for (int jt = 0; jt < 2; ++jt) {
                bf16x8 a = *(const bf16x8*)(kw1b + (jt * 16 + le) * 128 + ks * 32 + g * 8);
                acc[jt] = __builtin_amdgcn_mfma_f32_16x16x32_bf16(a, b, acc[jt], 0, 0, 0);
            }
        }
        const int e = e0 + w * 16 + le;
#pragma unroll
        for (int jt = 0; jt < 2; ++jt) {
            int h = jt * 16 + g * 4;
            ushort4 o;
            o.x = f2bf(fmaxf(acc[jt][0] + kb1s[h + 0], 0.f));
            o.y = f2bf(fmaxf(acc[jt][1] + kb1s[h + 1], 0.f));
            o.z = f2bf(fmaxf(acc[jt][2] + kb1s[h + 2], 0.f));
            o.w = f2bf(fmaxf(acc[jt][3] + kb1s[h + 3], 0.f));
            *(ushort4*)(hid_b + (size_t)e * KHD + h) = o;
        }
    } else {
        // ---------------- pack branch (Wb2 / W0b / w2b) + cnt zero ----------------
        int idx = (blockIdx.x - (NN / 64 + NE / 64)) * 256 + t;
        if (idx < 33 * 4096) {
            int h = idx >> 12, r = idx & 4095;
            int half = r >> 11, wq = (r >> 9) & 3, ln = (r >> 3) & 63, k = r & 7;
            int gq = ln >> 4, lq = ln & 15;
            int row = wq * 16 + lq, col = half * 32 + gq * 8 + k;
            float v = (h < 32) ? kw2[(size_t)h * 4160 + 64 + (size_t)row * 64 + col]
                               : kb2[64 + row * 64 + col];
            Wb2[idx] = f2bf(v);
            return;
        }
        idx -= 33 * 4096;
        if (idx < 2048) { int j = idx >> 5, h = idx & 31; W0b[idx] = f2bf(kw2[(size_t)h * 4160 + j]); return; }
        idx -= 2048;
        if (idx < 16384) { int c = idx >> 6, k = idx & 63; w2b[idx] = f2bf(w2[(size_t)k * 256 + c]); return; }
        idx -= 16384;
        if (idx < NN) cnt[idx] = 0;
    }
}

// ---------------- kernel D: fused bilinear via MFMA (128 edges/block, 4 waves) -----------
__global__ __launch_bounds__(256) void k_edge(
    const unsigned short* __restrict__ msgn_b,   // [NN][64]
    const unsigned short* __restrict__ hid_b,    // [NE][32]
    const int* __restrict__ elist, const float* __restrict__ eweight,
    int* __restrict__ cnt,
    const unsigned short* __restrict__ Wb2,      // [33][2][4][64*8] per-lane-linear
    const unsigned short* __restrict__ W0b,      // [64][32]
    const float* __restrict__ kb2,
    unsigned short* __restrict__ msg_out)        // [NN][DCAP][64] bf16 buckets, *eweight
{
    __shared__ __align__(16) float hids[128 * HS];
    __shared__ int eposs[128];
    const int t = threadIdx.x;
    const int w = t >> 6, le = t & 15, g = (t >> 4) & 3;
    const int lane = t & 63;
    const int e0 = blockIdx.x * 128;

    if (t < 128) {   // claim bucket slots for this block's edges
        int no = elist[(size_t)(e0 + t) * 2 + 1];
        eposs[t] = no * DCAP + atomicAdd(&cnt[no], 1);
    }

    for (int q = t; q < 1024; q += 256) {
        int e = q >> 3, h4 = (q & 7) * 4;
        ushort4 hh = *(const ushort4*)(hid_b + (size_t)(e0 + e) * KHD + h4);
        float4 f; f.x = bf2f(hh.x); f.y = bf2f(hh.y); f.z = bf2f(hh.z); f.w = bf2f(hh.w);
        *(float4*)(hids + e * HS + h4) = f;
    }
    if (t < 128) hids[t * HS + 32] = 1.0f;

    int eid[8];
#pragma unroll
    for (int nt = 0; nt < 8; ++nt) eid[nt] = e0 + nt * 16 + le;

    bf16x8 bm[8][2];
#pragma unroll
    for (int nt = 0; nt < 8; ++nt) {
        int ni = elist[(size_t)eid[nt] * 2];
#pragma unroll
        for (int ks = 0; ks < 2; ++ks)
            bm[nt][ks] = *(const bf16x8*)(msgn_b + (size_t)ni * HD + ks * 32 + g * 8);
    }

    const f32x4 zz = {0.f, 0.f, 0.f, 0.f};
    f32x4 acc[8];
    {   // r=0 block: A[j][h]=kw2[h,j], B=hid (bf16), K=32
        bf16x8 a0 = *(const bf16x8*)(W0b + (w * 16 + le) * KHD + g * 8);
#pragma unroll
        for (int nt = 0; nt < 8; ++nt) {
            bf16x8 hb = *(const bf16x8*)(hid_b + (size_t)eid[nt] * KHD + g * 8);
            acc[nt] = __builtin_amdgcn_mfma_f32_16x16x32_bf16(a0, hb, zz, 0, 0, 0);
        }
    }
    __syncthreads();

    int ep[8];
#pragma unroll
    for (int nt = 0; nt < 8; ++nt) ep[nt] = eposs[nt * 16 + le];

#pragma unroll 3
    for (int h = 0; h < 33; ++h) {
        float hv[8];
#pragma unroll
        for (int nt = 0; nt < 8; ++nt) hv[nt] = hids[(nt * 16 + le) * HS + h];
        const unsigned short* wrow = Wb2 + (size_t)h * 4096 + w * 512 + lane * 8;
        bf16x8 a0 = *(const bf16x8*)(wrow);
        bf16x8 a1 = *(const bf16x8*)(wrow + 2048);
#pragma unroll
        for (int nt = 0; nt < 8; ++nt) {
            f32x4 c = __builtin_amdgcn_mfma_f32_16x16x32_bf16(a0, bm[nt][0], zz, 0, 0, 0);
            c = __builtin_amdgcn_mfma_f32_16x16x32_bf16(a1, bm[nt][1], c, 0, 0, 0);
            acc[nt] += hv[nt] * c;
        }
    }

    const int j = w * 16 + g * 4;
    float4 kbv = *(const float4*)(kb2 + j);
#pragma unroll
    for (int nt = 0; nt < 8; ++nt) {
        float ew = eweight[eid[nt]];
        ushort4 o;
        o.x = f2bf((acc[nt][0] + kbv.x) * ew);
        o.y = f2bf((acc[nt][1] + kbv.y) * ew);
        o.z = f2bf((acc[nt][2] + kbv.z) * ew);
        o.w = f2bf((acc[nt][3] + kbv.w) * ew);
        *(ushort4*)(msg_out + (size_t)ep[nt] * HD + j) = o;
    }
}

// ---------------- kernel E: bucket segment-sum (bf16x8 vectorized) + BN + GEMM + BN -------
__global__ __launch_bounds__(256) void k_out(
    const unsigned short* __restrict__ msg_out,  // [NN][DCAP][64]
    const int* __restrict__ cnt,
    const unsigned short* __restrict__ w2b, const float* __restrict__ b2,
    const float* __restrict__ g_u, const float* __restrict__ be_u,
    const float* __restrict__ m_u, const float* __restrict__ v_u,
    const float* __restrict__ g_o, const float* __restrict__ be_o,
    const float* __restrict__ m_o, const float* __restrict__ v_o,
    float* __restrict__ out)
{
    __shared__ __align__(16) unsigned short utb[64 * UTS];
    __shared__ __align__(16) float sc_o[DOUT], sho2[DOUT], sc_u[HD], sh_u[HD];
    const int t = threadIdx.x;
    const int n0 = blockIdx.x * 64;
    {
        float s = g_o[t] * rsqrtf(v_o[t] + BN_EPS);
        sc_o[t] = s; sho2[t] = b2[t] * s + (be_o[t] - m_o[t] * s);
        if (t < HD) {
            float s2 = g_u[t] * rsqrtf(v_u[t] + BN_EPS);
            sc_u[t] = s2; sh_u[t] = be_u[t] - m_u[t] * s2;
        }
    }
    __syncthreads();
    {
        const int lane8 = t & 7, grp = t >> 3;   // grp 0..31
#pragma unroll
        for (int rr = 0; rr < 2; ++rr) {
            const int r = grp * 2 + rr;          // 0..63
            const int n = n0 + r;
            const int pc = cnt[n];
            const unsigned short* base = msg_out + (size_t)n * DCAP * HD + lane8 * 8;
            float a[8];
#pragma unroll
            for (int i = 0; i < 8; ++i) a[i] = 0.f;
            for (int p = 0; p < pc; ++p) {
                bf16x8 v = *(const bf16x8*)(base + (size_t)p * HD);
#pragma unroll
                for (int i = 0; i < 8; ++i) a[i] += bf2f((unsigned short)v[i]);
            }
            const int j = lane8 * 8;
            ushort4 o0, o1;
            o0.x = f2bf(fmaxf(fmaf(a[0], sc_u[j + 0], sh_u[j + 0]), 0.f));
            o0.y = f2bf(fmaxf(fmaf(a[1], sc_u[j + 1], sh_u[j + 1]), 0.f));
            o0.z = f2bf(fmaxf(fmaf(a[2], sc_u[j + 2], sh_u[j + 2]), 0.f));
            o0.w = f2bf(fmaxf(fmaf(a[3], sc_u[j + 3], sh_u[j + 3]), 0.f));
            o1.x = f2bf(fmaxf(fmaf(a[4], sc_u[j + 4], sh_u[j + 4]), 0.f));
            o1.y = f2bf(fmaxf(fmaf(a[5], sc_u[j + 5], sh_u[j + 5]), 0.f));
            o1.z = f2bf(fmaxf(fmaf(a[6], sc_u[j + 6], sh_u[j + 6]), 0.f));
            o1.w = f2bf(fmaxf(fmaf(a[7], sc_u[j + 7], sh_u[j + 7]), 0.f));
            *(ushort4*)(utb + r * UTS + j) = o0;
            *(ushort4*)(utb + r * UTS + j + 4) = o1;
        }
    }
    __syncthreads();
    const int w = t >> 6, le = t & 15, g = (t >> 4) & 3;
    const f32x4 zz = {0.f, 0.f, 0.f, 0.f};
    f32x4 acc[4][4];
#pragma unroll
    for (int jt = 0; jt < 4; ++jt)
#pragma unroll
        for (int nt = 0; nt < 4; ++nt) acc[jt][nt] = zz;
#pragma unroll
    for (int ks = 0; ks < 2; ++ks) {
        bf16x8 b[4];
#pragma unroll
        for (int nt = 0; nt < 4; ++nt)
            b[nt] = *(const bf16x8*)(utb + (nt * 16 + le) * UTS + ks * 32 + g * 8);
#pragma unroll
        for (int jt = 0; jt < 4; ++jt) {
            bf16x8 a = *(const bf16x8*)(w2b + (size_t)(w * 64 + jt * 16 + le) * HD + ks * 32 + g * 8);
#pragma unroll
            for (int nt = 0; nt < 4; ++nt)
                acc[jt][nt] = __builtin_amdgcn_mfma_f32_16x16x32_bf16(a, b[nt], acc[jt][nt], 0, 0, 0);
        }
    }
#pragma unroll
    for (int jt = 0; jt < 4; ++jt) {
        int c = w * 64 + jt * 16 + g * 4;
        float4 sc = *(const float4*)(sc_o + c);
        float4 sh = *(const float4*)(sho2 + c);
#pragma unroll
        for (int nt = 0; nt < 4; ++nt) {
            int n = n0 + nt * 16 + le;
            float4 o;
            o.x = fmaf(acc[jt][nt][0], sc.x, sh.x);
            o.y = fmaf(acc[jt][nt][1], sc.y, sh.y);
            o.z = fmaf(acc[jt][nt][2], sc.z, sh.z);
            o.w = fmaf(acc[jt][nt][3], sc.w, sh.w);
            *(float4*)(out + (size_t)n * DOUT + c) = o;
        }
    }
}

extern "C" void kernel_launch(void* const* d_in, const int* in_sizes, int n_in,
                              void* d_out, int out_size, void* d_ws, size_t ws_size,
                              hipStream_t stream)
{
    (void)in_sizes; (void)n_in; (void)out_size; (void)ws_size;
    const float* x    = (const float*)d_in[0];
    const float* ei   = (const float*)d_in[1];
    const int*   el   = (const int*)  d_in[2];
    const float* ew   = (const float*)d_in[3];
    const float* w1   = (const float*)d_in[4];
    const float* b1   = (const float*)d_in[5];
    const float* kw1  = (const float*)d_in[6];
    const float* kb1  = (const float*)d_in[7];
    const float* kw2  = (const float*)d_in[8];
    const float* kb2  = (const float*)d_in[9];
    const float* w2   = (const float*)d_in[10];
    const float* b2   = (const float*)d_in[11];
    const float* g_in = (const float*)d_in[12], *be_in = (const float*)d_in[13];
    const float* m_in = (const float*)d_in[14], *v_in  = (const float*)d_in[15];
    const float* g_m  = (const float*)d_in[16], *be_m  = (const float*)d_in[17];
    const float* m_m  = (const float*)d_in[18], *v_m   = (const float*)d_in[19];
    const float* g_u  = (const float*)d_in[20], *be_u  = (const float*)d_in[21];
    const float* m_u  = (const float*)d_in[22], *v_u   = (const float*)d_in[23];
    const float* g_o  = (const float*)d_in[24], *be_o  = (const float*)d_in[25];
    const float* m_o  = (const float*)d_in[26], *v_o   = (const float*)d_in[27];

    char* wsb = (char*)d_ws;
    size_t off = 0;
    auto alloc = [&](size_t bytes) -> void* {
        void* p = wsb + off; off += (bytes + 255) & ~(size_t)255; return p;
    };
    unsigned short* msgn_b  = (unsigned short*)alloc((size_t)NN * HD * 2);
    unsigned short* hid_b   = (unsigned short*)alloc((size_t)NE * KHD * 2);
    unsigned short* Wb2     = (unsigned short*)alloc((size_t)33 * 4096 * 2);
    unsigned short* W0b     = (unsigned short*)alloc((size_t)64 * KHD * 2);
    unsigned short* w1b     = (unsigned short*)alloc((size_t)HD * DIN * 2);
    unsigned short* kw1b    = (unsigned short*)alloc((size_t)KHD * DE * 2);
    unsigned short* w2b     = (unsigned short*)alloc((size_t)DOUT * HD * 2);
    int* cnt = (int*)alloc((size_t)NN * 4);
    unsigned short* msg_out = (unsigned short*)alloc((size_t)NN * DCAP * HD * 2);

    hipLaunchKernelGGL(k_prepw, dim3(80), dim3(256), 0, stream, w1, kw1, w1b, kw1b);
    hipLaunchKernelGGL(k_mh, dim3(NN / 64 + NE / 64 + 663), dim3(256), 0, stream,
                       x, w1b, b1, g_in, be_in, m_in, v_in, g_m, be_m, m_m, v_m, msgn_b,
                       ei, kw1b, kb1, hid_b, kw2, kb2, w2, Wb2, W0b, w2b, cnt);
    hipLaunchKernelGGL(k_edge, dim3(NE / 128), dim3(256), 0, stream,
                       msgn_b, hid_b, el, ew, cnt, Wb2, W0b, kb2, msg_out);
    hipLaunchKernelGGL(k_out, dim3(NN / 64), dim3(256), 0, stream,
                       msg_out, cnt, w2b, b2, g_u, be_u, m_u, v_u,
                       g_o, be_o, m_o, v_o, (float*)d_out);
}

// Round 23
// 71.317 us; speedup vs baseline: 1.4327x; 1.0060x over previous
//
#include <hip/hip_runtime.h>

#define NN   16000
#define NE   64000
#define DIN  256
#define HD   64
#define DOUT 256
#define DE   128
#define KHD  32
#define DCAP 32
#define BN_EPS 1e-5f
#define LNS 264
#define EIS 136
#define HS  36
#define UTS 72

typedef __attribute__((ext_vector_type(8))) short bf16x8;
typedef __attribute__((ext_vector_type(4))) float f32x4;

__device__ __forceinline__ unsigned short f2bf(float f) {
    unsigned int u = __float_as_uint(f);
    u += 0x7fff + ((u >> 16) & 1);
    return (unsigned short)(u >> 16);
}
__device__ __forceinline__ float bf2f(unsigned short s) {
    return __uint_as_float(((unsigned int)s) << 16);
}

// ---------------- kernel PW: pack only w1b/kw1b (needed by k_mh) -------------------------
__global__ __launch_bounds__(256) void k_prepw(
    const float* __restrict__ w1, const float* __restrict__ kw1,
    unsigned short* __restrict__ w1b, unsigned short* __restrict__ kw1b)
{
    int idx = blockIdx.x * 256 + threadIdx.x;
    if (idx < 16384) { int j = idx >> 8, k = idx & 255; w1b[idx] = f2bf(w1[(size_t)k * 64 + j]); return; }
    idx -= 16384;
    if (idx < 4096) { int h = idx >> 7, k = idx & 127; kw1b[idx] = f2bf(kw1[(size_t)k * 32 + h]); }
}

// ---------------- kernel MH: msgn (0..249) | hidden (250..1249) | pack+cntzero (1250..) --
__global__ __launch_bounds__(256) void k_mh(
    const float* __restrict__ x, const unsigned short* __restrict__ w1b,
    const float* __restrict__ b1,
    const float* __restrict__ g_in, const float* __restrict__ be_in,
    const float* __restrict__ m_in, const float* __restrict__ v_in,
    const float* __restrict__ g_m, const float* __restrict__ be_m,
    const float* __restrict__ m_m, const float* __restrict__ v_m,
    unsigned short* __restrict__ msgn_b,
    const float* __restrict__ ei, const unsigned short* __restrict__ kw1b,
    const float* __restrict__ kb1, unsigned short* __restrict__ hid_b,
    const float* __restrict__ kw2, const float* __restrict__ kb2,
    const float* __restrict__ w2,
    unsigned short* __restrict__ Wb2, unsigned short* __restrict__ W0b,
    unsigned short* __restrict__ w2b, int* __restrict__ cnt)
{
    __shared__ __align__(16) unsigned char smem[36608];
    const int t = threadIdx.x;
    const int w = t >> 6, le = t & 15, g = (t >> 4) & 3;
    const f32x4 zz = {0.f, 0.f, 0.f, 0.f};

    if (blockIdx.x < NN / 64) {
        // ---------------- msgn branch ----------------
        unsigned short* lnb = (unsigned short*)smem;
        float* sc_in = (float*)(smem + 33792);
        float* sh_in = (float*)(smem + 34816);
        float* sc_m  = (float*)(smem + 35840);
        float* shm2  = (float*)(smem + 36096);
        const int n0 = blockIdx.x * 64;
        {
            float s = g_in[t] * rsqrtf(v_in[t] + BN_EPS);
            sc_in[t] = s; sh_in[t] = be_in[t] - m_in[t] * s;
            if (t < HD) {
                float s2 = g_m[t] * rsqrtf(v_m[t] + BN_EPS);
                sc_m[t] = s2; shm2[t] = b1[t] * s2 + (be_m[t] - m_m[t] * s2);
            }
        }
        __syncthreads();
        for (int i = t; i < 64 * 64; i += 256) {
            int row = i >> 6, c4 = (i & 63) * 4;
            float4 xx = *(const float4*)(x + (size_t)(n0 + row) * DIN + c4);
            float4 sc = *(const float4*)(sc_in + c4);
            float4 sh = *(const float4*)(sh_in + c4);
            ushort4 o;
            o.x = f2bf(fmaxf(fmaf(xx.x, sc.x, sh.x), 0.f));
            o.y = f2bf(fmaxf(fmaf(xx.y, sc.y, sh.y), 0.f));
            o.z = f2bf(fmaxf(fmaf(xx.z, sc.z, sh.z), 0.f));
            o.w = f2bf(fmaxf(fmaf(xx.w, sc.w, sh.w), 0.f));
            *(ushort4*)(lnb + row * LNS + c4) = o;
        }
        __syncthreads();
        f32x4 acc[4] = {zz, zz, zz, zz};
#pragma unroll
        for (int ks = 0; ks < 8; ++ks) {
            bf16x8 b = *(const bf16x8*)(lnb + (w * 16 + le) * LNS + ks * 32 + g * 8);
#pragma unroll
            for (int jt = 0; jt < 4; ++jt) {
                bf16x8 a = *(const bf16x8*)(w1b + (jt * 16 + le) * 256 + ks * 32 + g * 8);
                acc[jt] = __builtin_amdgcn_mfma_f32_16x16x32_bf16(a, b, acc[jt], 0, 0, 0);
            }
        }
        const int n = n0 + w * 16 + le;
#pragma unroll
        for (int jt = 0; jt < 4; ++jt) {
            int j = jt * 16 + g * 4;
            float4 sc = *(const float4*)(sc_m + j);
            float4 sh = *(const float4*)(shm2 + j);
            ushort4 o;
            o.x = f2bf(fmaxf(fmaf(acc[jt][0], sc.x, sh.x), 0.f));
            o.y = f2bf(fmaxf(fmaf(acc[jt][1], sc.y, sh.y), 0.f));
            o.z = f2bf(fmaxf(fmaf(acc[jt][2], sc.z, sh.z), 0.f));
            o.w = f2bf(fmaxf(fmaf(acc[jt][3], sc.w, sh.w), 0.f));
            *(ushort4*)(msgn_b + (size_t)n * HD + j) = o;
        }
    } else if (blockIdx.x < NN / 64 + NE / 64) {
        // ---------------- hidden branch ----------------
        unsigned short* eib = (unsigned short*)smem;
        float* kb1s = (float*)(smem + 17408);
        const int e0 = (blockIdx.x - NN / 64) * 64;
        if (t < KHD) kb1s[t] = kb1[t];
        for (int i = t; i < 64 * 32; i += 256) {
            int row = i >> 5, c4 = (i & 31) * 4;
            float4 xx = *(const float4*)(ei + (size_t)(e0 + row) * DE + c4);
            ushort4 o;
            o.x = f2bf(xx.x); o.y = f2bf(xx.y); o.z = f2bf(xx.z); o.w = f2bf(xx.w);
            *(ushort4*)(eib + row * EIS + c4) = o;
        }
        __syncthreads();
        f32x4 acc[2] = {zz, zz};
#pragma unroll
        for (int ks = 0; ks < 4; ++ks) {
            bf16x8 b = *(const bf16x8*)(eib + (w * 16 + le) * EIS + ks * 32 + g * 8);
#pragma unroll
            for (int jt = 0; jt < 2; ++jt) {
                bf16x8 a = *(const bf16x8*)(kw1b + (jt * 16 + le) * 128 + ks * 32 + g * 8);
                acc[jt] = __builtin_amdgcn_mfma_f32_16x16x32_bf16(a, b, acc[jt], 0, 0, 0);
            }
        }
        const int e = e0 + w * 16 + le;
#pragma unroll
        for (int jt = 0; jt < 2; ++jt) {
            int h = jt * 16 + g * 4;
            ushort4 o;
            o.x = f2bf(fmaxf(acc[jt][0] + kb1s[h + 0], 0.f));
            o.y = f2bf(fmaxf(acc[jt][1] + kb1s[h + 1], 0.f));
            o.z = f2bf(fmaxf(acc[jt][2] + kb1s[h + 2], 0.f));
            o.w = f2bf(fmaxf(acc[jt][3] + kb1s[h + 3], 0.f));
            *(ushort4*)(hid_b + (size_t)e * KHD + h) = o;
        }
    } else {
        // ---------------- pack branch (Wb2 / W0b / w2b) + cnt zero ----------------
        int idx = (blockIdx.x - (NN / 64 + NE / 64)) * 256 + t;
        if (idx < 33 * 4096) {
            int h = idx >> 12, r = idx & 4095;
            int half = r >> 11, wq = (r >> 9) & 3, ln = (r >> 3) & 63, k = r & 7;
            int gq = ln >> 4, lq = ln & 15;
            int row = wq * 16 + lq, col = half * 32 + gq * 8 + k;
            float v = (h < 32) ? kw2[(size_t)h * 4160 + 64 + (size_t)row * 64 + col]
                               : kb2[64 + row * 64 + col];
            Wb2[idx] = f2bf(v);
            return;
        }
        idx -= 33 * 4096;
        if (idx < 2048) { int j = idx >> 5, h = idx & 31; W0b[idx] = f2bf(kw2[(size_t)h * 4160 + j]); return; }
        idx -= 2048;
        if (idx < 16384) { int c = idx >> 6, k = idx & 63; w2b[idx] = f2bf(w2[(size_t)k * 256 + c]); return; }
        idx -= 16384;
        if (idx < NN) cnt[idx] = 0;
    }
}

// ---------------- kernel D: fused bilinear via MFMA (128 edges/block, 4 waves) -----------
// h-loop FULLY unrolled: 33 straight-line iterations let the scheduler hoist the 66
// independent Wb2 loads arbitrarily far ahead of their MFMAs (unroll-3 pinned them).
__global__ __launch_bounds__(256) void k_edge(
    const unsigned short* __restrict__ msgn_b,   // [NN][64]
    const unsigned short* __restrict__ hid_b,    // [NE][32]
    const int* __restrict__ elist, const float* __restrict__ eweight,
    int* __restrict__ cnt,
    const unsigned short* __restrict__ Wb2,      // [33][2][4][64*8] per-lane-linear
    const unsigned short* __restrict__ W0b,      // [64][32]
    const float* __restrict__ kb2,
    unsigned short* __restrict__ msg_out)        // [NN][DCAP][64] bf16 buckets, *eweight
{
    __shared__ __align__(16) float hids[128 * HS];
    __shared__ int eposs[128];
    const int t = threadIdx.x;
    const int w = t >> 6, le = t & 15, g = (t >> 4) & 3;
    const int lane = t & 63;
    const int e0 = blockIdx.x * 128;

    if (t < 128) {   // claim bucket slots for this block's edges
        int no = elist[(size_t)(e0 + t) * 2 + 1];
        eposs[t] = no * DCAP + atomicAdd(&cnt[no], 1);
    }

    for (int q = t; q < 1024; q += 256) {
        int e = q >> 3, h4 = (q & 7) * 4;
        ushort4 hh = *(const ushort4*)(hid_b + (size_t)(e0 + e) * KHD + h4);
        float4 f; f.x = bf2f(hh.x); f.y = bf2f(hh.y); f.z = bf2f(hh.z); f.w = bf2f(hh.w);
        *(float4*)(hids + e * HS + h4) = f;
    }
    if (t < 128) hids[t * HS + 32] = 1.0f;

    int eid[8];
#pragma unroll
    for (int nt = 0; nt < 8; ++nt) eid[nt] = e0 + nt * 16 + le;

    bf16x8 bm[8][2];
#pragma unroll
    for (int nt = 0; nt < 8; ++nt) {
        int ni = elist[(size_t)eid[nt] * 2];
#pragma unroll
        for (int ks = 0; ks < 2; ++ks)
            bm[nt][ks] = *(const bf16x8*)(msgn_b + (size_t)ni * HD + ks * 32 + g * 8);
    }

    const f32x4 zz = {0.f, 0.f, 0.f, 0.f};
    f32x4 acc[8];
    {   // r=0 block: A[j][h]=kw2[h,j], B=hid (bf16), K=32
        bf16x8 a0 = *(const bf16x8*)(W0b + (w * 16 + le) * KHD + g * 8);
#pragma unroll
        for (int nt = 0; nt < 8; ++nt) {
            bf16x8 hb = *(const bf16x8*)(hid_b + (size_t)eid[nt] * KHD + g * 8);
            acc[nt] = __builtin_amdgcn_mfma_f32_16x16x32_bf16(a0, hb, zz, 0, 0, 0);
        }
    }
    __syncthreads();

    int ep[8];
#pragma unroll
    for (int nt = 0; nt < 8; ++nt) ep[nt] = eposs[nt * 16 + le];

#pragma unroll
    for (int h = 0; h < 33; ++h) {
        float hv[8];
#pragma unroll
        for (int nt = 0; nt < 8; ++nt) hv[nt] = hids[(nt * 16 + le) * HS + h];
        const unsigned short* wrow = Wb2 + (size_t)h * 4096 + w * 512 + lane * 8;
        bf16x8 a0 = *(const bf16x8*)(wrow);
        bf16x8 a1 = *(const bf16x8*)(wrow + 2048);
#pragma unroll
        for (int nt = 0; nt < 8; ++nt) {
            f32x4 c = __builtin_amdgcn_mfma_f32_16x16x32_bf16(a0, bm[nt][0], zz, 0, 0, 0);
            c = __builtin_amdgcn_mfma_f32_16x16x32_bf16(a1, bm[nt][1], c, 0, 0, 0);
            acc[nt] += hv[nt] * c;
        }
    }

    const int j = w * 16 + g * 4;
    float4 kbv = *(const float4*)(kb2 + j);
#pragma unroll
    for (int nt = 0; nt < 8; ++nt) {
        float ew = eweight[eid[nt]];
        ushort4 o;
        o.x = f2bf((acc[nt][0] + kbv.x) * ew);
        o.y = f2bf((acc[nt][1] + kbv.y) * ew);
        o.z = f2bf((acc[nt][2] + kbv.z) * ew);
        o.w = f2bf((acc[nt][3] + kbv.w) * ew);
        *(ushort4*)(msg_out + (size_t)ep[nt] * HD + j) = o;
    }
}

// ---------------- kernel E: bucket segment-sum (bf16x8 vectorized) + BN + GEMM + BN -------
__global__ __launch_bounds__(256) void k_out(
    const unsigned short* __restrict__ msg_out,  // [NN][DCAP][64]
    const int* __restrict__ cnt,
    const unsigned short* __restrict__ w2b, const float* __restrict__ b2,
    const float* __restrict__ g_u, const float* __restrict__ be_u,
    const float* __restrict__ m_u, const float* __restrict__ v_u,
    const float* __restrict__ g_o, const float* __restrict__ be_o,
    const float* __restrict__ m_o, const float* __restrict__ v_o,
    float* __restrict__ out)
{
    __shared__ __align__(16) unsigned short utb[64 * UTS];
    __shared__ __align__(16) float sc_o[DOUT], sho2[DOUT], sc_u[HD], sh_u[HD];
    const int t = threadIdx.x;
    const int n0 = blockIdx.x * 64;
    {
        float s = g_o[t] * rsqrtf(v_o[t] + BN_EPS);
        sc_o[t] = s; sho2[t] = b2[t] * s + (be_o[t] - m_o[t] * s);
        if (t < HD) {
            float s2 = g_u[t] * rsqrtf(v_u[t] + BN_EPS);
            sc_u[t] = s2; sh_u[t] = be_u[t] - m_u[t] * s2;
        }
    }
    __syncthreads();
    {
        const int lane8 = t & 7, grp = t >> 3;   // grp 0..31
#pragma unroll
        for (int rr = 0; rr < 2; ++rr) {
            const int r = grp * 2 + rr;          // 0..63
            const int n = n0 + r;
            const int pc = cnt[n];
            const unsigned short* base = msg_out + (size_t)n * DCAP * HD + lane8 * 8;
            float a[8];
#pragma unroll
            for (int i = 0; i < 8; ++i) a[i] = 0.f;
            for (int p = 0; p < pc; ++p) {
                bf16x8 v = *(const bf16x8*)(base + (size_t)p * HD);
#pragma unroll
                for (int i = 0; i < 8; ++i) a[i] += bf2f((unsigned short)v[i]);
            }
            const int j = lane8 * 8;
            ushort4 o0, o1;
            o0.x = f2bf(fmaxf(fmaf(a[0], sc_u[j + 0], sh_u[j + 0]), 0.f));
            o0.y = f2bf(fmaxf(fmaf(a[1], sc_u[j + 1], sh_u[j + 1]), 0.f));
            o0.z = f2bf(fmaxf(fmaf(a[2], sc_u[j + 2], sh_u[j + 2]), 0.f));
            o0.w = f2bf(fmaxf(fmaf(a[3], sc_u[j + 3], sh_u[j + 3]), 0.f));
            o1.x = f2bf(fmaxf(fmaf(a[4], sc_u[j + 4], sh_u[j + 4]), 0.f));
            o1.y = f2bf(fmaxf(fmaf(a[5], sc_u[j + 5], sh_u[j + 5]), 0.f));
            o1.z = f2bf(fmaxf(fmaf(a[6], sc_u[j + 6], sh_u[j + 6]), 0.f));
            o1.w = f2bf(fmaxf(fmaf(a[7], sc_u[j + 7], sh_u[j + 7]), 0.f));
            *(ushort4*)(utb + r * UTS + j) = o0;
            *(ushort4*)(utb + r * UTS + j + 4) = o1;
        }
    }
    __syncthreads();
    const int w = t >> 6, le = t & 15, g = (t >> 4) & 3;
    const f32x4 zz = {0.f, 0.f, 0.f, 0.f};
    f32x4 acc[4][4];
#pragma unroll
    for (int jt = 0; jt < 4; ++jt)
#pragma unroll
        for (int nt = 0; nt < 4; ++nt) acc[jt][nt] = zz;
#pragma unroll
    for (int ks = 0; ks < 2; ++ks) {
        bf16x8 b[4];
#pragma unroll
        for (int nt = 0; nt < 4; ++nt)
            b[nt] = *(const bf16x8*)(utb + (nt * 16 + le) * UTS + ks * 32 + g * 8);
#pragma unroll
        for (int jt = 0; jt < 4; ++jt) {
            bf16x8 a = *(const bf16x8*)(w2b + (size_t)(w * 64 + jt * 16 + le) * HD + ks * 32 + g * 8);
#pragma unroll
            for (int nt = 0; nt < 4; ++nt)
                acc[jt][nt] = __builtin_amdgcn_mfma_f32_16x16x32_bf16(a, b[nt], acc[jt][nt], 0, 0, 0);
        }
    }
#pragma unroll
    for (int jt = 0; jt < 4; ++jt) {
        int c = w * 64 + jt * 16 + g * 4;
        float4 sc = *(const float4*)(sc_o + c);
        float4 sh = *(const float4*)(sho2 + c);
#pragma unroll
        for (int nt = 0; nt < 4; ++nt) {
            int n = n0 + nt * 16 + le;
            float4 o;
            o.x = fmaf(acc[jt][nt][0], sc.x, sh.x);
            o.y = fmaf(acc[jt][nt][1], sc.y, sh.y);
            o.z = fmaf(acc[jt][nt][2], sc.z, sh.z);
            o.w = fmaf(acc[jt][nt][3], sc.w, sh.w);
            *(float4*)(out + (size_t)n * DOUT + c) = o;
        }
    }
}

extern "C" void kernel_launch(void* const* d_in, const int* in_sizes, int n_in,
                              void* d_out, int out_size, void* d_ws, size_t ws_size,
                              hipStream_t stream)
{
    (void)in_sizes; (void)n_in; (void)out_size; (void)ws_size;
    const float* x    = (const float*)d_in[0];
    const float* ei   = (const float*)d_in[1];
    const int*   el   = (const int*)  d_in[2];
    const float* ew   = (const float*)d_in[3];
    const float* w1   = (const float*)d_in[4];
    const float* b1   = (const float*)d_in[5];
    const float* kw1  = (const float*)d_in[6];
    const float* kb1  = (const float*)d_in[7];
    const float* kw2  = (const float*)d_in[8];
    const float* kb2  = (const float*)d_in[9];
    const float* w2   = (const float*)d_in[10];
    const float* b2   = (const float*)d_in[11];
    const float* g_in = (const float*)d_in[12], *be_in = (const float*)d_in[13];
    const float* m_in = (const float*)d_in[14], *v_in  = (const float*)d_in[15];
    const float* g_m  = (const float*)d_in[16], *be_m  = (const float*)d_in[17];
    const float* m_m  = (const float*)d_in[18], *v_m   = (const float*)d_in[19];
    const float* g_u  = (const float*)d_in[20], *be_u  = (const float*)d_in[21];
    const float* m_u  = (const float*)d_in[22], *v_u   = (const float*)d_in[23];
    const float* g_o  = (const float*)d_in[24], *be_o  = (const float*)d_in[25];
    const float* m_o  = (const float*)d_in[26], *v_o   = (const float*)d_in[27];

    char* wsb = (char*)d_ws;
    size_t off = 0;
    auto alloc = [&](size_t bytes) -> void* {
        void* p = wsb + off; off += (bytes + 255) & ~(size_t)255; return p;
    };
    unsigned short* msgn_b  = (unsigned short*)alloc((size_t)NN * HD * 2);
    unsigned short* hid_b   = (unsigned short*)alloc((size_t)NE * KHD * 2);
    unsigned short* Wb2     = (unsigned short*)alloc((size_t)33 * 4096 * 2);
    unsigned short* W0b     = (unsigned short*)alloc((size_t)64 * KHD * 2);
    unsigned short* w1b     = (unsigned short*)alloc((size_t)HD * DIN * 2);
    unsigned short* kw1b    = (unsigned short*)alloc((size_t)KHD * DE * 2);
    unsigned short* w2b     = (unsigned short*)alloc((size_t)DOUT * HD * 2);
    int* cnt = (int*)alloc((size_t)NN * 4);
    unsigned short* msg_out = (unsigned short*)alloc((size_t)NN * DCAP * HD * 2);

    hipLaunchKernelGGL(k_prepw, dim3(80), dim3(256), 0, stream, w1, kw1, w1b, kw1b);
    hipLaunchKernelGGL(k_mh, dim3(NN / 64 + NE / 64 + 663), dim3(256), 0, stream,
                       x, w1b, b1, g_in, be_in, m_in, v_in, g_m, be_m, m_m, v_m, msgn_b,
                       ei, kw1b, kb1, hid_b, kw2, kb2, w2, Wb2, W0b, w2b, cnt);
    hipLaunchKernelGGL(k_edge, dim3(NE / 128), dim3(256), 0, stream,
                       msgn_b, hid_b, el, ew, cnt, Wb2, W0b, kb2, msg_out);
    hipLaunchKernelGGL(k_out, dim3(NN / 64), dim3(256), 0, stream,
                       msg_out, cnt, w2b, b2, g_u, be_u, m_u, v_u,
                       g_o, be_o, m_o, v_o, (float*)d_out);
}